// Round 4
// baseline (3778.027 us; speedup 1.0000x reference)
//
#include <hip/hip_runtime.h>
#include <cstdint>

#define D 128
#define BK 64              // rows per bucket
#define CAP 1536           // per-bucket edge capacity (mean 1024, +16 sigma)
#define CHUNK 4096         // edges per place block
#define NBK_MAX 1568       // compile-time LDS bound (>= MPAD/64 = 1564)

typedef short   bf8_t    __attribute__((ext_vector_type(8)));   // 8 bf16 (4 VGPR)
typedef float   f4_t     __attribute__((ext_vector_type(4)));
typedef unsigned short u8x16_t __attribute__((ext_vector_type(8))); // 8 x u16

__device__ __forceinline__ float bf2f(unsigned short u) {
    unsigned v = ((unsigned)u) << 16; float f; __builtin_memcpy(&f, &v, 4); return f;
}
__device__ __forceinline__ unsigned short f2bf(float f) {
    unsigned v; __builtin_memcpy(&v, &f, 4);
    v = v + 0x7FFFu + ((v >> 16) & 1u);      // round-to-nearest-even
    return (unsigned short)(v >> 16);
}

// ---------------------------------------------------------------------------
// 0. h_all (f32, split item/user) -> h_bf (bf16, zero-padded to MPAD rows)
//    one thread per 8 floats
// ---------------------------------------------------------------------------
__global__ __launch_bounds__(256) void convert_kernel(
    const float* __restrict__ h_item, const float* __restrict__ h_user,
    unsigned short* __restrict__ h_bf, int Ni, int N)
{
    int idx = blockIdx.x * 256 + threadIdx.x;
    size_t base = (size_t)idx * 8;
    int row = idx >> 4;                      // 16 threads per 128-wide row
    u8x16_t us = {};
    if (row < N) {
        const float* src = (row < Ni) ? h_item + base
                                      : h_user + (base - (size_t)Ni * D);
        float4 a0 = *reinterpret_cast<const float4*>(src);
        float4 a1 = *reinterpret_cast<const float4*>(src + 4);
        us[0]=f2bf(a0.x); us[1]=f2bf(a0.y); us[2]=f2bf(a0.z); us[3]=f2bf(a0.w);
        us[4]=f2bf(a1.x); us[5]=f2bf(a1.y); us[6]=f2bf(a1.z); us[7]=f2bf(a1.w);
    }
    *reinterpret_cast<u8x16_t*>(h_bf + base) = us;
}

// ---------------------------------------------------------------------------
// 1. bucket-place: edges -> fixed-capacity 64-row buckets, LDS-aggregated.
//    ev[b*CAP + k] = { (row&63)<<17 | col , val }
//    bcnt stride 16 ints (64B) to avoid atomic line contention.
// ---------------------------------------------------------------------------
__global__ __launch_bounds__(256) void place_kernel(
    const int* __restrict__ rows, const int* __restrict__ cols,
    const float* __restrict__ vals, int* __restrict__ bcnt,
    uint2* __restrict__ ev, int E, int nbk)
{
    __shared__ int cnt[NBK_MAX];
    __shared__ int base[NBK_MAX];
    const int tid = threadIdx.x;
    const int e0 = blockIdx.x * CHUNK;
    const int ecnt = min(CHUNK, E - e0);

    for (int b = tid; b < nbk; b += 256) cnt[b] = 0;
    __syncthreads();
    for (int i = tid; i < ecnt; i += 256)
        atomicAdd(&cnt[rows[e0 + i] >> 6], 1);
    __syncthreads();
    for (int b = tid; b < nbk; b += 256) {
        int c = cnt[b];
        base[b] = c ? atomicAdd(&bcnt[b * 16], c) : 0;
        cnt[b] = 0;                           // reuse as phase-2 cursor
    }
    __syncthreads();
    for (int i = tid; i < ecnt; i += 256) {
        int r = rows[e0 + i];
        int b = r >> 6;
        int pos = base[b] + atomicAdd(&cnt[b], 1);
        if (pos < CAP)
            ev[(size_t)b * CAP + pos] =
                make_uint2(((unsigned)(r & 63) << 17) | (unsigned)cols[e0 + i],
                           __float_as_uint(vals[e0 + i]));
    }
}

// ---------------------------------------------------------------------------
// 2. bucket accumulate: block per bucket, acc[64][128] f32 in LDS.
//    8-deep gather pipeline of hr rows; ds_add_f32; then coalesced X RMW.
//    FIRST: X = bf16(h_bf + acc); else X = bf16(X + acc).
// ---------------------------------------------------------------------------
template<int FIRST>
__global__ __launch_bounds__(256) void accum_kernel(
    const unsigned short* __restrict__ hr, const uint2* __restrict__ ev,
    const int* __restrict__ bcnt, const unsigned short* __restrict__ h_bf,
    unsigned short* __restrict__ X)
{
    __shared__ float acc[BK * D];            // 32 KB
    const int tid = threadIdx.x;
    const int lane = tid & 63;
    const int wv = tid >> 6;
    const int b = blockIdx.x;

    #pragma unroll
    for (int i = 0; i < 8; ++i)
        *reinterpret_cast<f4_t*>(&acc[(i * 256 + tid) * 4]) = f4_t{0.f,0.f,0.f,0.f};
    __syncthreads();

    int cnt = min(bcnt[b * 16], CAP);
    const uint2* eb = ev + (size_t)b * CAP;
    int s = (cnt * wv) >> 2;
    int e = (cnt * (wv + 1)) >> 2;

    int p = s;
    for (; p + 8 <= e; p += 8) {
        uint2 ee[8];
        #pragma unroll
        for (int j = 0; j < 8; ++j) ee[j] = eb[p + j];
        ushort2 gg[8];
        #pragma unroll
        for (int j = 0; j < 8; ++j)
            gg[j] = *reinterpret_cast<const ushort2*>(
                hr + ((size_t)(ee[j].x & 0x1FFFFu) << 7) + lane * 2);
        #pragma unroll
        for (int j = 0; j < 8; ++j) {
            float v = __uint_as_float(ee[j].y);
            int lr = ee[j].x >> 17;
            atomicAdd(&acc[(lr << 7) + lane * 2],     v * bf2f(gg[j].x));
            atomicAdd(&acc[(lr << 7) + lane * 2 + 1], v * bf2f(gg[j].y));
        }
    }
    for (; p < e; ++p) {
        uint2 ee = eb[p];
        ushort2 g = *reinterpret_cast<const ushort2*>(
            hr + ((size_t)(ee.x & 0x1FFFFu) << 7) + lane * 2);
        float v = __uint_as_float(ee.y);
        int lr = ee.x >> 17;
        atomicAdd(&acc[(lr << 7) + lane * 2],     v * bf2f(g.x));
        atomicAdd(&acc[(lr << 7) + lane * 2 + 1], v * bf2f(g.y));
    }
    __syncthreads();

    #pragma unroll
    for (int i = 0; i < 16; ++i) {
        int lr = wv * 16 + i;
        size_t go = ((size_t)b * BK + lr) * D + lane * 2;
        float a0 = acc[(lr << 7) + lane * 2];
        float a1 = acc[(lr << 7) + lane * 2 + 1];
        ushort2 prev = FIRST
            ? *reinterpret_cast<const ushort2*>(h_bf + go)
            : *reinterpret_cast<const ushort2*>(X + go);
        a0 += bf2f(prev.x); a1 += bf2f(prev.y);
        *reinterpret_cast<ushort2*>(X + go) = make_ushort2(f2bf(a0), f2bf(a1));
    }
}

// ---------------------------------------------------------------------------
// MFMA GEMM, M x 128 @ (128x128)^T, K = 128. A = bf16 (padded, unguarded).
// 128-row tile, 4 waves (2x2), per wave 64x64 = 4x4 frags of 16x16x32.
// FINAL 0: out = bf16 tile, unguarded. FINAL 1: f32 + bias + relu, guarded.
// ---------------------------------------------------------------------------
template<int FINAL>
__global__ __launch_bounds__(256) void gemm128(
    const unsigned short* __restrict__ A, const float* __restrict__ Wf,
    const float* __restrict__ biasp, void* __restrict__ outp, int Mvalid)
{
    __shared__ char LDS[2 * 128 * 272];          // 69632 B
    char* As = LDS;
    char* Bs = LDS + 128 * 272;
    const int tid  = threadIdx.x;
    const int lane = tid & 63;
    const int wv   = tid >> 6;
    const int row0 = blockIdx.x * 128;

    // stage B: W (f32 row-major [n][k]) -> bf16 LDS
    #pragma unroll
    for (int i = 0; i < 8; ++i) {
        int idx = i * 256 + tid;
        int r = idx >> 4, u = idx & 15;
        const float* wp = Wf + r * D + u * 8;
        float4 w0 = *reinterpret_cast<const float4*>(wp);
        float4 w1 = *reinterpret_cast<const float4*>(wp + 4);
        u8x16_t us;
        us[0]=f2bf(w0.x); us[1]=f2bf(w0.y); us[2]=f2bf(w0.z); us[3]=f2bf(w0.w);
        us[4]=f2bf(w1.x); us[5]=f2bf(w1.y); us[6]=f2bf(w1.z); us[7]=f2bf(w1.w);
        *reinterpret_cast<u8x16_t*>(&Bs[r * 272 + u * 16]) = us;
    }
    // stage A (bf16, rows padded -> unguarded)
    #pragma unroll
    for (int i = 0; i < 8; ++i) {
        int idx = i * 256 + tid;
        int r = idx >> 4, u = idx & 15;
        u8x16_t us = *reinterpret_cast<const u8x16_t*>(
            A + (size_t)(row0 + r) * D + u * 8);
        *reinterpret_cast<u8x16_t*>(&As[r * 272 + u * 16]) = us;
    }
    __syncthreads();

    const int wm = wv >> 1, wn = wv & 1;
    f4_t acc[4][4] = {};

    #pragma unroll
    for (int kk = 0; kk < 4; ++kk) {
        const int ku = kk * 4 + (lane >> 4);
        bf8_t a[4], bfr[4];
        #pragma unroll
        for (int mi = 0; mi < 4; ++mi) {
            int r = wm * 64 + mi * 16 + (lane & 15);
            a[mi] = *reinterpret_cast<const bf8_t*>(&As[r * 272 + ku * 16]);
        }
        #pragma unroll
        for (int nj = 0; nj < 4; ++nj) {
            int r = wn * 64 + nj * 16 + (lane & 15);
            bfr[nj] = *reinterpret_cast<const bf8_t*>(&Bs[r * 272 + ku * 16]);
        }
        #pragma unroll
        for (int mi = 0; mi < 4; ++mi)
            #pragma unroll
            for (int nj = 0; nj < 4; ++nj)
                acc[mi][nj] = __builtin_amdgcn_mfma_f32_16x16x32_bf16(
                    a[mi], bfr[nj], acc[mi][nj], 0, 0, 0);
    }
    __syncthreads();

    if (FINAL == 0) {
        #pragma unroll
        for (int mi = 0; mi < 4; ++mi)
            #pragma unroll
            for (int nj = 0; nj < 4; ++nj)
                #pragma unroll
                for (int q = 0; q < 4; ++q) {
                    int r = wm * 64 + mi * 16 + (lane >> 4) * 4 + q;
                    int c = wn * 64 + nj * 16 + (lane & 15);
                    *reinterpret_cast<unsigned short*>(&As[r * 272 + c * 2]) =
                        f2bf(acc[mi][nj][q]);
                }
        __syncthreads();
        #pragma unroll
        for (int i = 0; i < 8; ++i) {
            int idx = i * 256 + tid;
            int r = idx >> 4, u = idx & 15;
            u8x16_t v = *reinterpret_cast<const u8x16_t*>(&As[r * 272 + u * 16]);
            *reinterpret_cast<u8x16_t*>(
                (unsigned short*)outp + (size_t)(row0 + r) * D + u * 8) = v;
        }
    } else {
        #pragma unroll
        for (int mi = 0; mi < 4; ++mi)
            #pragma unroll
            for (int nj = 0; nj < 4; ++nj)
                #pragma unroll
                for (int q = 0; q < 4; ++q) {
                    int r = wm * 64 + mi * 16 + (lane >> 4) * 4 + q;
                    int c = wn * 64 + nj * 16 + (lane & 15);
                    *reinterpret_cast<float*>(&LDS[r * 544 + c * 4]) = acc[mi][nj][q];
                }
        __syncthreads();
        #pragma unroll
        for (int i = 0; i < 16; ++i) {
            int idx = i * 256 + tid;
            int r = idx >> 5, u = idx & 31;
            int gr = row0 + r;
            if (gr < Mvalid) {
                f4_t v = *reinterpret_cast<const f4_t*>(&LDS[r * 544 + u * 16]);
                float4 bb = *reinterpret_cast<const float4*>(biasp + u * 4);
                v[0] = fmaxf(v[0] + bb.x, 0.f);
                v[1] = fmaxf(v[1] + bb.y, 0.f);
                v[2] = fmaxf(v[2] + bb.z, 0.f);
                v[3] = fmaxf(v[3] + bb.w, 0.f);
                *reinterpret_cast<f4_t*>((float*)outp + (size_t)gr * D + u * 4) = v;
            }
        }
    }
}

// ---------------------------------------------------------------------------
extern "C" void kernel_launch(void* const* d_in, const int* in_sizes, int n_in,
                              void* d_out, int out_size, void* d_ws, size_t ws_size,
                              hipStream_t stream)
{
    const float* h_item = (const float*)d_in[0];
    const float* h_user = (const float*)d_in[1];
    const float* W_rel  = (const float*)d_in[2];
    const float* W_item = (const float*)d_in[3];
    const float* b_item = (const float*)d_in[4];
    const float* W_user = (const float*)d_in[5];
    const float* b_user = (const float*)d_in[6];
    const float* vals   = (const float*)d_in[7];
    const int*   rows   = (const int*)d_in[8];
    const int*   cols   = (const int*)d_in[9];

    const int Ni = in_sizes[0] / D;              // 80000
    const int Nu = in_sizes[1] / D;              // 20000
    const int N  = Ni + Nu;                      // 100000
    const int NR = in_sizes[2] / (D * D);        // 3
    const int E  = in_sizes[7] / NR;             // 1,600,000
    const int MPAD = ((N + 127) / 128) * 128;    // 100096
    const int NBKP = MPAD / BK;                  // 1564 (incl. pad bucket)
    const int nbk  = (N + BK - 1) / BK;          // 1563 (buckets with real rows)

    // workspace carve (~96 MB), 256B-aligned
    auto align_up = [](size_t x) { return (x + 255) & ~(size_t)255; };
    char* p = (char*)d_ws;
    unsigned short* h_bf = (unsigned short*)p; p += align_up((size_t)MPAD * D * 2);
    unsigned short* X    = (unsigned short*)p; p += align_up((size_t)MPAD * D * 2);
    unsigned short* hr   = (unsigned short*)p; p += align_up((size_t)MPAD * D * 2);
    uint2* ev            = (uint2*)p;          p += align_up((size_t)NBKP * CAP * 8);
    int*   bcnt3         = (int*)p;            p += align_up((size_t)3 * NBKP * 16 * 4);
    float* out = (float*)d_out;

    hipMemsetAsync(bcnt3, 0, (size_t)3 * NBKP * 16 * sizeof(int), stream);
    convert_kernel<<<MPAD * 16 / 256, 256, 0, stream>>>(h_item, h_user, h_bf, Ni, N);

    const int pblocks = (E + CHUNK - 1) / CHUNK;
    for (int r = 0; r < NR; ++r) {
        int* bcnt = bcnt3 + (size_t)r * NBKP * 16;
        gemm128<0><<<MPAD / 128, 256, 0, stream>>>(
            h_bf, W_rel + (size_t)r * D * D, nullptr, hr, 0);
        place_kernel<<<pblocks, 256, 0, stream>>>(
            rows + (size_t)r * E, cols + (size_t)r * E, vals + (size_t)r * E,
            bcnt, ev, E, nbk);
        if (r == 0)
            accum_kernel<1><<<NBKP, 256, 0, stream>>>(hr, ev, bcnt, h_bf, X);
        else
            accum_kernel<0><<<NBKP, 256, 0, stream>>>(hr, ev, bcnt, h_bf, X);
    }

    gemm128<1><<<(Ni + 127) / 128, 256, 0, stream>>>(X, W_item, b_item, out, Ni);
    gemm128<1><<<(MPAD - Ni) / 128, 256, 0, stream>>>(
        X + (size_t)Ni * D, W_user, b_user, out + (size_t)Ni * D, Nu);
}

// Round 5
// 513.922 us; speedup vs baseline: 7.3514x; 7.3514x over previous
//
#include <hip/hip_runtime.h>
#include <cstdint>

#define D 128
#define BK 64              // rows per bucket
#define CAP 1536           // per-bucket edge capacity (mean 1024, +16 sigma)
#define CHUNK 4096         // edges per place block
#define NBK_MAX 1568       // compile-time LDS bound (>= MPAD/64 = 1564)

typedef short   bf8_t    __attribute__((ext_vector_type(8)));   // 8 bf16 (4 VGPR)
typedef float   f4_t     __attribute__((ext_vector_type(4)));
typedef unsigned short u8x16_t __attribute__((ext_vector_type(8))); // 8 x u16

__device__ __forceinline__ float bf2f(unsigned short u) {
    unsigned v = ((unsigned)u) << 16; float f; __builtin_memcpy(&f, &v, 4); return f;
}
__device__ __forceinline__ unsigned short f2bf(float f) {
    unsigned v; __builtin_memcpy(&v, &f, 4);
    v = v + 0x7FFFu + ((v >> 16) & 1u);      // round-to-nearest-even
    return (unsigned short)(v >> 16);
}

// ---------------------------------------------------------------------------
// 0. h_all (f32, split item/user) -> h_bf (bf16, zero-padded to MPAD rows)
// ---------------------------------------------------------------------------
__global__ __launch_bounds__(256) void convert_kernel(
    const float* __restrict__ h_item, const float* __restrict__ h_user,
    unsigned short* __restrict__ h_bf, int Ni, int N)
{
    int idx = blockIdx.x * 256 + threadIdx.x;
    size_t base = (size_t)idx * 8;
    int row = idx >> 4;                      // 16 threads per 128-wide row
    u8x16_t us = {};
    if (row < N) {
        const float* src = (row < Ni) ? h_item + base
                                      : h_user + (base - (size_t)Ni * D);
        float4 a0 = *reinterpret_cast<const float4*>(src);
        float4 a1 = *reinterpret_cast<const float4*>(src + 4);
        us[0]=f2bf(a0.x); us[1]=f2bf(a0.y); us[2]=f2bf(a0.z); us[3]=f2bf(a0.w);
        us[4]=f2bf(a1.x); us[5]=f2bf(a1.y); us[6]=f2bf(a1.z); us[7]=f2bf(a1.w);
    }
    *reinterpret_cast<u8x16_t*>(h_bf + base) = us;
}

// ---------------------------------------------------------------------------
// 1. bucket-place: edges -> fixed-capacity 64-row buckets, LDS-aggregated.
//    ev[b*CAP + k] = { (row&63)<<17 | col , val }
// ---------------------------------------------------------------------------
__global__ __launch_bounds__(256) void place_kernel(
    const int* __restrict__ rows, const int* __restrict__ cols,
    const float* __restrict__ vals, int* __restrict__ bcnt,
    uint2* __restrict__ ev, int E, int nbk)
{
    __shared__ int cnt[NBK_MAX];
    __shared__ int base[NBK_MAX];
    const int tid = threadIdx.x;
    const int e0 = blockIdx.x * CHUNK;
    const int ecnt = min(CHUNK, E - e0);

    for (int b = tid; b < nbk; b += 256) cnt[b] = 0;
    __syncthreads();
    for (int i = tid; i < ecnt; i += 256)
        atomicAdd(&cnt[rows[e0 + i] >> 6], 1);
    __syncthreads();
    for (int b = tid; b < nbk; b += 256) {
        int c = cnt[b];
        base[b] = c ? atomicAdd(&bcnt[b * 16], c) : 0;
        cnt[b] = 0;                           // reuse as phase-2 cursor
    }
    __syncthreads();
    for (int i = tid; i < ecnt; i += 256) {
        int r = rows[e0 + i];
        int b = r >> 6;
        int pos = base[b] + atomicAdd(&cnt[b], 1);
        if (pos < CAP)
            ev[(size_t)b * CAP + pos] =
                make_uint2(((unsigned)(r & 63) << 17) | (unsigned)cols[e0 + i],
                           __float_as_uint(vals[e0 + i]));
    }
}

// ---------------------------------------------------------------------------
// 2. in-bucket counting sort (block per bucket, all in LDS):
//    load bucket edges -> 64-bin hist -> wave scan -> scatter row-sorted
//    back to ev (tag stripped: entries become {col, val}), emit per-row
//    [rstart, rend) global ranges.
// ---------------------------------------------------------------------------
__global__ __launch_bounds__(256) void sort_kernel(
    const int* __restrict__ bcnt, uint2* __restrict__ ev,
    int* __restrict__ rstart, int* __restrict__ rend, int N)
{
    __shared__ uint2 se[CAP];                // 12 KB
    __shared__ int hist[BK], cur[BK];
    const int tid = threadIdx.x;
    const int b = blockIdx.x;
    const int cnt = min(bcnt[b * 16], CAP);

    for (int i = tid; i < cnt; i += 256) se[i] = ev[(size_t)b * CAP + i];
    if (tid < BK) hist[tid] = 0;
    __syncthreads();
    for (int i = tid; i < cnt; i += 256)
        atomicAdd(&hist[se[i].x >> 17], 1);
    __syncthreads();
    if (tid < BK) {                          // wave 0: 64-bin exclusive scan
        int x = hist[tid], orig = x;
        #pragma unroll
        for (int d = 1; d < 64; d <<= 1) {
            int y = __shfl_up(x, d);
            if (tid >= d) x += y;
        }
        cur[tid] = x - orig;
        int g = b * BK + tid;
        if (g < N) {
            rstart[g] = b * CAP + x - orig;
            rend[g]   = b * CAP + x;
        }
    }
    __syncthreads();
    for (int i = tid; i < cnt; i += 256) {
        uint2 x = se[i];
        int pos = atomicAdd(&cur[x.x >> 17], 1);
        ev[(size_t)b * CAP + pos] = make_uint2(x.x & 0x1FFFFu, x.y);
    }
}

// ---------------------------------------------------------------------------
// 3. per-row gather-accumulate: one wave per row, 4-wide gather group with
//    rolling ev prefetch. FIRST: X = bf16(h_bf + sum); else X = bf16(X + sum).
// ---------------------------------------------------------------------------
template<int FIRST>
__global__ __launch_bounds__(256) void accum_row(
    const unsigned short* __restrict__ hr, const uint2* __restrict__ ev,
    const int* __restrict__ rstart, const int* __restrict__ rend,
    const unsigned short* __restrict__ h_bf, unsigned short* __restrict__ X,
    int N)
{
    int row = blockIdx.x * 4 + (threadIdx.x >> 6);
    if (row >= N) return;
    const int lane = threadIdx.x & 63;
    int s = rstart[row], t = rend[row];

    float a0, a1;
    if (FIRST) {
        ushort2 hv = *reinterpret_cast<const ushort2*>(h_bf + (size_t)row * D + lane * 2);
        a0 = bf2f(hv.x); a1 = bf2f(hv.y);
    } else {
        if (s == t) return;
        ushort2 xv = *reinterpret_cast<const ushort2*>(X + (size_t)row * D + lane * 2);
        a0 = bf2f(xv.x); a1 = bf2f(xv.y);
    }

    int p = s;
    uint2 e0, e1, e2, e3;
    if (p + 4 <= t) { e0 = ev[p]; e1 = ev[p+1]; e2 = ev[p+2]; e3 = ev[p+3]; }
    while (p + 4 <= t) {
        ushort2 g0 = *reinterpret_cast<const ushort2*>(hr + ((size_t)e0.x << 7) + lane * 2);
        ushort2 g1 = *reinterpret_cast<const ushort2*>(hr + ((size_t)e1.x << 7) + lane * 2);
        ushort2 g2 = *reinterpret_cast<const ushort2*>(hr + ((size_t)e2.x << 7) + lane * 2);
        ushort2 g3 = *reinterpret_cast<const ushort2*>(hr + ((size_t)e3.x << 7) + lane * 2);
        int pn = p + 4;
        uint2 f0 = e0, f1 = e1, f2 = e2, f3 = e3;
        if (pn + 4 <= t) { f0 = ev[pn]; f1 = ev[pn+1]; f2 = ev[pn+2]; f3 = ev[pn+3]; }
        a0 = fmaf(__uint_as_float(e0.y), bf2f(g0.x), a0);
        a1 = fmaf(__uint_as_float(e0.y), bf2f(g0.y), a1);
        a0 = fmaf(__uint_as_float(e1.y), bf2f(g1.x), a0);
        a1 = fmaf(__uint_as_float(e1.y), bf2f(g1.y), a1);
        a0 = fmaf(__uint_as_float(e2.y), bf2f(g2.x), a0);
        a1 = fmaf(__uint_as_float(e2.y), bf2f(g2.y), a1);
        a0 = fmaf(__uint_as_float(e3.y), bf2f(g3.x), a0);
        a1 = fmaf(__uint_as_float(e3.y), bf2f(g3.y), a1);
        e0 = f0; e1 = f1; e2 = f2; e3 = f3;
        p = pn;
    }
    for (; p < t; ++p) {
        uint2 ee = ev[p];
        ushort2 g = *reinterpret_cast<const ushort2*>(hr + ((size_t)ee.x << 7) + lane * 2);
        a0 = fmaf(__uint_as_float(ee.y), bf2f(g.x), a0);
        a1 = fmaf(__uint_as_float(ee.y), bf2f(g.y), a1);
    }
    *reinterpret_cast<ushort2*>(X + (size_t)row * D + lane * 2) =
        make_ushort2(f2bf(a0), f2bf(a1));
}

// ---------------------------------------------------------------------------
// MFMA GEMM, M x 128 @ (128x128)^T, K = 128. A = bf16 (padded, unguarded).
// 128-row tile, 4 waves (2x2), per wave 64x64 = 4x4 frags of 16x16x32.
// FINAL 0: out = bf16 tile, unguarded. FINAL 1: f32 + bias + relu, guarded.
// ---------------------------------------------------------------------------
template<int FINAL>
__global__ __launch_bounds__(256) void gemm128(
    const unsigned short* __restrict__ A, const float* __restrict__ Wf,
    const float* __restrict__ biasp, void* __restrict__ outp, int Mvalid)
{
    __shared__ char LDS[2 * 128 * 272];          // 69632 B
    char* As = LDS;
    char* Bs = LDS + 128 * 272;
    const int tid  = threadIdx.x;
    const int lane = tid & 63;
    const int wv   = tid >> 6;
    const int row0 = blockIdx.x * 128;

    // stage B: W (f32 row-major [n][k]) -> bf16 LDS
    #pragma unroll
    for (int i = 0; i < 8; ++i) {
        int idx = i * 256 + tid;
        int r = idx >> 4, u = idx & 15;
        const float* wp = Wf + r * D + u * 8;
        float4 w0 = *reinterpret_cast<const float4*>(wp);
        float4 w1 = *reinterpret_cast<const float4*>(wp + 4);
        u8x16_t us;
        us[0]=f2bf(w0.x); us[1]=f2bf(w0.y); us[2]=f2bf(w0.z); us[3]=f2bf(w0.w);
        us[4]=f2bf(w1.x); us[5]=f2bf(w1.y); us[6]=f2bf(w1.z); us[7]=f2bf(w1.w);
        *reinterpret_cast<u8x16_t*>(&Bs[r * 272 + u * 16]) = us;
    }
    // stage A (bf16, rows padded -> unguarded)
    #pragma unroll
    for (int i = 0; i < 8; ++i) {
        int idx = i * 256 + tid;
        int r = idx >> 4, u = idx & 15;
        u8x16_t us = *reinterpret_cast<const u8x16_t*>(
            A + (size_t)(row0 + r) * D + u * 8);
        *reinterpret_cast<u8x16_t*>(&As[r * 272 + u * 16]) = us;
    }
    __syncthreads();

    const int wm = wv >> 1, wn = wv & 1;
    f4_t acc[4][4] = {};

    #pragma unroll
    for (int kk = 0; kk < 4; ++kk) {
        const int ku = kk * 4 + (lane >> 4);
        bf8_t a[4], bfr[4];
        #pragma unroll
        for (int mi = 0; mi < 4; ++mi) {
            int r = wm * 64 + mi * 16 + (lane & 15);
            a[mi] = *reinterpret_cast<const bf8_t*>(&As[r * 272 + ku * 16]);
        }
        #pragma unroll
        for (int nj = 0; nj < 4; ++nj) {
            int r = wn * 64 + nj * 16 + (lane & 15);
            bfr[nj] = *reinterpret_cast<const bf8_t*>(&Bs[r * 272 + ku * 16]);
        }
        #pragma unroll
        for (int mi = 0; mi < 4; ++mi)
            #pragma unroll
            for (int nj = 0; nj < 4; ++nj)
                acc[mi][nj] = __builtin_amdgcn_mfma_f32_16x16x32_bf16(
                    a[mi], bfr[nj], acc[mi][nj], 0, 0, 0);
    }
    __syncthreads();

    if (FINAL == 0) {
        #pragma unroll
        for (int mi = 0; mi < 4; ++mi)
            #pragma unroll
            for (int nj = 0; nj < 4; ++nj)
                #pragma unroll
                for (int q = 0; q < 4; ++q) {
                    int r = wm * 64 + mi * 16 + (lane >> 4) * 4 + q;
                    int c = wn * 64 + nj * 16 + (lane & 15);
                    *reinterpret_cast<unsigned short*>(&As[r * 272 + c * 2]) =
                        f2bf(acc[mi][nj][q]);
                }
        __syncthreads();
        #pragma unroll
        for (int i = 0; i < 8; ++i) {
            int idx = i * 256 + tid;
            int r = idx >> 4, u = idx & 15;
            u8x16_t v = *reinterpret_cast<const u8x16_t*>(&As[r * 272 + u * 16]);
            *reinterpret_cast<u8x16_t*>(
                (unsigned short*)outp + (size_t)(row0 + r) * D + u * 8) = v;
        }
    } else {
        #pragma unroll
        for (int mi = 0; mi < 4; ++mi)
            #pragma unroll
            for (int nj = 0; nj < 4; ++nj)
                #pragma unroll
                for (int q = 0; q < 4; ++q) {
                    int r = wm * 64 + mi * 16 + (lane >> 4) * 4 + q;
                    int c = wn * 64 + nj * 16 + (lane & 15);
                    *reinterpret_cast<float*>(&LDS[r * 544 + c * 4]) = acc[mi][nj][q];
                }
        __syncthreads();
        #pragma unroll
        for (int i = 0; i < 16; ++i) {
            int idx = i * 256 + tid;
            int r = idx >> 5, u = idx & 31;
            int gr = row0 + r;
            if (gr < Mvalid) {
                f4_t v = *reinterpret_cast<const f4_t*>(&LDS[r * 544 + u * 16]);
                float4 bb = *reinterpret_cast<const float4*>(biasp + u * 4);
                v[0] = fmaxf(v[0] + bb.x, 0.f);
                v[1] = fmaxf(v[1] + bb.y, 0.f);
                v[2] = fmaxf(v[2] + bb.z, 0.f);
                v[3] = fmaxf(v[3] + bb.w, 0.f);
                *reinterpret_cast<f4_t*>((float*)outp + (size_t)gr * D + u * 4) = v;
            }
        }
    }
}

// ---------------------------------------------------------------------------
extern "C" void kernel_launch(void* const* d_in, const int* in_sizes, int n_in,
                              void* d_out, int out_size, void* d_ws, size_t ws_size,
                              hipStream_t stream)
{
    const float* h_item = (const float*)d_in[0];
    const float* h_user = (const float*)d_in[1];
    const float* W_rel  = (const float*)d_in[2];
    const float* W_item = (const float*)d_in[3];
    const float* b_item = (const float*)d_in[4];
    const float* W_user = (const float*)d_in[5];
    const float* b_user = (const float*)d_in[6];
    const float* vals   = (const float*)d_in[7];
    const int*   rows   = (const int*)d_in[8];
    const int*   cols   = (const int*)d_in[9];

    const int Ni = in_sizes[0] / D;              // 80000
    const int Nu = in_sizes[1] / D;              // 20000
    const int N  = Ni + Nu;                      // 100000
    const int NR = in_sizes[2] / (D * D);        // 3
    const int E  = in_sizes[7] / NR;             // 1,600,000
    const int MPAD = ((N + 127) / 128) * 128;    // 100096
    const int NBKP = MPAD / BK;                  // 1564
    const int nbk  = (N + BK - 1) / BK;          // 1563

    // workspace carve (~97 MB), 256B-aligned
    auto align_up = [](size_t x) { return (x + 255) & ~(size_t)255; };
    char* p = (char*)d_ws;
    unsigned short* h_bf = (unsigned short*)p; p += align_up((size_t)MPAD * D * 2);
    unsigned short* X    = (unsigned short*)p; p += align_up((size_t)MPAD * D * 2);
    unsigned short* hr   = (unsigned short*)p; p += align_up((size_t)MPAD * D * 2);
    uint2* ev            = (uint2*)p;          p += align_up((size_t)NBKP * CAP * 8);
    int*   bcnt3         = (int*)p;            p += align_up((size_t)3 * NBKP * 16 * 4);
    int*   rstart        = (int*)p;            p += align_up((size_t)N * 4);
    int*   rend          = (int*)p;            p += align_up((size_t)N * 4);
    float* out = (float*)d_out;

    hipMemsetAsync(bcnt3, 0, (size_t)3 * NBKP * 16 * sizeof(int), stream);
    convert_kernel<<<MPAD * 16 / 256, 256, 0, stream>>>(h_item, h_user, h_bf, Ni, N);

    const int pblocks = (E + CHUNK - 1) / CHUNK;
    for (int r = 0; r < NR; ++r) {
        int* bcnt = bcnt3 + (size_t)r * NBKP * 16;
        gemm128<0><<<MPAD / 128, 256, 0, stream>>>(
            h_bf, W_rel + (size_t)r * D * D, nullptr, hr, 0);
        place_kernel<<<pblocks, 256, 0, stream>>>(
            rows + (size_t)r * E, cols + (size_t)r * E, vals + (size_t)r * E,
            bcnt, ev, E, nbk);
        sort_kernel<<<nbk, 256, 0, stream>>>(bcnt, ev, rstart, rend, N);
        if (r == 0)
            accum_row<1><<<(N + 3) / 4, 256, 0, stream>>>(
                hr, ev, rstart, rend, h_bf, X, N);
        else
            accum_row<0><<<(N + 3) / 4, 256, 0, stream>>>(
                hr, ev, rstart, rend, h_bf, X, N);
    }

    gemm128<1><<<(Ni + 127) / 128, 256, 0, stream>>>(X, W_item, b_item, out, Ni);
    gemm128<1><<<(MPAD - Ni) / 128, 256, 0, stream>>>(
        X + (size_t)Ni * D, W_user, b_user, out + (size_t)Ni * D, Nu);
}